// Round 7
// baseline (440.054 us; speedup 1.0000x reference)
//
#include <hip/hip_runtime.h>
#include <cstddef>
#include <cstdint>

#define T_DIM 2048
#define E_DIM 1024
#define M_DIM 4096   // T*B rows, row index = t*2 + b

typedef __attribute__((ext_vector_type(8))) short short8;      // 8 fp16 bit-patterns
typedef __attribute__((ext_vector_type(8))) _Float16 half8;    // mfma f16 A/B (x32)
typedef __attribute__((ext_vector_type(4))) _Float16 half4;    // mfma f16 A/B (x16)
typedef __attribute__((ext_vector_type(4))) float f32x4;       // mfma C/D

__device__ __forceinline__ short f16_bits(float v) {
  return __builtin_bit_cast(short, (_Float16)v);
}
__device__ __forceinline__ unsigned int pk2(float a, float b) {
  return __builtin_bit_cast(unsigned int, __builtin_amdgcn_cvt_pkrtz(a, b));
}
__device__ __forceinline__ half8 h8(short8 s) { return __builtin_bit_cast(half8, s); }

// async global->LDS, 16B per lane; LDS dest = wave-uniform base + lane*16
__device__ __forceinline__ void gl_lds16(const short* g, const short* l) {
  __builtin_amdgcn_global_load_lds(
      (const __attribute__((address_space(1))) unsigned int*)g,
      (__attribute__((address_space(3))) unsigned int*)l, 16, 0, 0);
}

// ---------------------------------------------------------------------------
// fp32 -> fp16 (RNE). blocks: [0,4096) x ; then 1024 each wq, wk, wv, wo.
// ---------------------------------------------------------------------------
__global__ __launch_bounds__(256) void convert_all(
    const float* __restrict__ x, const float* __restrict__ wq,
    const float* __restrict__ wk, const float* __restrict__ wv,
    const float* __restrict__ wo,
    short* __restrict__ xh, short* __restrict__ wqh, short* __restrict__ wkh,
    short* __restrict__ wvh, short* __restrict__ woh)
{
  const int bid = blockIdx.x;
  const float* in; short* hi; int base;
  if (bid < 4096)      { in = x;  hi = xh;  base = 0;    }
  else if (bid < 5120) { in = wq; hi = wqh; base = 4096; }
  else if (bid < 6144) { in = wk; hi = wkh; base = 5120; }
  else if (bid < 7168) { in = wv; hi = wvh; base = 6144; }
  else                 { in = wo; hi = woh; base = 7168; }
  const int i = (bid - base) * 256 + threadIdx.x;     // float4 index
  float4 v = ((const float4*)in)[i];
  uint2 p;
  p.x = (unsigned short)f16_bits(v.x) | ((unsigned int)(unsigned short)f16_bits(v.y) << 16);
  p.y = (unsigned short)f16_bits(v.z) | ((unsigned int)(unsigned short)f16_bits(v.w) << 16);
  ((uint2*)hi)[i] = p;
}

// ---------------------------------------------------------------------------
// Fused QKV GEMM, fp16 (verified r5). C = (A @ W^T + bias) * scale.
// ---------------------------------------------------------------------------
__global__ __launch_bounds__(256) void gemm_qkv(
    const short* __restrict__ xh,
    const short* __restrict__ wqh, const short* __restrict__ wkh,
    const short* __restrict__ wvh,
    const float* __restrict__ bq, const float* __restrict__ bk,
    const float* __restrict__ bv,
    short* __restrict__ qo, short* __restrict__ ko, short* __restrict__ vto)
{
  __shared__ __align__(16) short smem[128 * 32 * 2];   // Ah | Wh ; reused as Tb
  short* Ah = smem;
  short* Wh = smem + 128 * 32;
  const int tid = threadIdx.x;
  const int lane = tid & 63;
  const int w = tid >> 6;
  const int quad = lane >> 4;
  const int l15 = lane & 15;
  const int sel = blockIdx.x >> 3;
  const int n0 = (blockIdx.x & 7) * 128;
  const int m0 = blockIdx.y * 128;

  const short* wsel = sel == 0 ? wqh : sel == 1 ? wkh : wvh;
  const float* bias = sel == 0 ? bq : sel == 1 ? bk : bv;
  const float scale = sel == 0 ? 0.125f * 1.44269504088896f : 1.0f;

  const short* gsrc = (w < 2) ? xh : wsel;
  short* lbuf = (w < 2) ? Ah : Wh;
  const int rbase = (w < 2) ? m0 : n0;
  const int jb = (w & 1) * 4;
  const int lrow = lane >> 2;
  const int gphys = lane & 3;

  f32x4 zero = {0.f, 0.f, 0.f, 0.f};
  f32x4 acc[4][4];
#pragma unroll
  for (int i = 0; i < 4; ++i)
#pragma unroll
    for (int j = 0; j < 4; ++j) acc[i][j] = zero;

  const int wm = w & 1, wn = w >> 1;

  for (int k0 = 0; k0 < E_DIM; k0 += 32) {
    __syncthreads();
#pragma unroll
    for (int jj = 0; jj < 4; ++jj) {
      int j = jb + jj;
      int r = j * 16 + lrow;
      int gl = (gphys - (r >> 1)) & 3;
      gl_lds16(gsrc + (size_t)(rbase + r) * E_DIM + k0 + gl * 8, lbuf + j * 512);
    }
    __syncthreads();
    short8 ahf[4];
#pragma unroll
    for (int i = 0; i < 4; ++i) {
      int r = wm * 64 + i * 16 + l15;
      int idx = r * 32 + ((quad + (r >> 1)) & 3) * 8;
      ahf[i] = *(const short8*)&Ah[idx];
    }
#pragma unroll
    for (int j = 0; j < 4; ++j) {
      int r = wn * 64 + j * 16 + l15;
      int idx = r * 32 + ((quad + (r >> 1)) & 3) * 8;
      short8 bhf = *(const short8*)&Wh[idx];
#pragma unroll
      for (int i = 0; i < 4; ++i)
        acc[i][j] = __builtin_amdgcn_mfma_f32_16x16x32_f16(h8(ahf[i]), h8(bhf), acc[i][j], 0, 0, 0);
    }
  }

  if (sel < 2) {
#pragma unroll
    for (int j = 0; j < 4; ++j) {
      const int gc = n0 + wn * 64 + j * 16 + l15;
      const float bb = bias[gc];
      const int h = gc >> 6, d = gc & 63;
      short* dst = sel == 0 ? qo : ko;
#pragma unroll
      for (int i = 0; i < 4; ++i)
#pragma unroll
        for (int reg = 0; reg < 4; ++reg) {
          const int gm = m0 + wm * 64 + i * 16 + quad * 4 + reg;
          const float val = (acc[i][j][reg] + bb) * scale;
          const int t = gm >> 1, b = gm & 1;
          dst[((size_t)(b * 16 + h) * T_DIM + t) * 64 + d] = f16_bits(val);
        }
    }
  } else {
    short* Tb = smem;   // 64 * 128 * 2B = 16KB
    const int by = blockIdx.y;
#pragma unroll
    for (int R = 0; R < 2; ++R) {
      __syncthreads();
      if (wn == R) {
#pragma unroll
        for (int j = 0; j < 4; ++j) {
          const int nl = j * 16 + l15;
          const int gc = n0 + R * 64 + nl;
          const float bb = bias[gc];
#pragma unroll
          for (int i = 0; i < 4; ++i) {
            const int tp = wm * 32 + i * 8 + quad * 2;
            unsigned int lo = pk2(acc[i][j][0] + bb, acc[i][j][2] + bb);
            unsigned int hi = pk2(acc[i][j][1] + bb, acc[i][j][3] + bb);
            const int g0 = tp >> 3;
            const int sub = tp & 7;
            *(unsigned int*)&Tb[nl * 128 + ((g0 + nl) & 15) * 8 + sub] = lo;
            *(unsigned int*)&Tb[nl * 128 + ((g0 + 8 + nl) & 15) * 8 + sub] = hi;
          }
        }
      }
      __syncthreads();
#pragma unroll
      for (int ii = 0; ii < 4; ++ii) {
        const int n = w * 16 + ii * 4 + quad;
        const int g = (l15 - n) & 15;
        short8 vvec = *(const short8*)&Tb[n * 128 + l15 * 8];
        const int gc = n0 + R * 64 + n;
        const int h = gc >> 6, d = gc & 63;
        const int b = g >> 3;
        const int t = by * 64 + (g & 7) * 8;
        *(short8*)&vto[((size_t)(b * 16 + h) * 64 + d) * T_DIM + t] = vvec;
      }
    }
  }
}

// ---------------------------------------------------------------------------
// Output projection GEMM, split-K=2: partial = attn @ wo^T over K half
// (blockIdx.z selects half and target buffer). Grid (8,32,2) -> 512 blocks
// = 2 blocks/CU (r6 had 256 = 1/CU: barrier drain fully exposed).
// ---------------------------------------------------------------------------
__global__ __launch_bounds__(256) void gemm_out(
    const short* __restrict__ attn, const short* __restrict__ woh,
    float* __restrict__ p0, float* __restrict__ p1)
{
  __shared__ __align__(16) short Ah[128 * 32], Wh[128 * 32];
  const int tid = threadIdx.x;
  const int lane = tid & 63;
  const int w = tid >> 6;
  const int quad = lane >> 4;
  const int l15 = lane & 15;
  const int n0 = blockIdx.x * 128;
  const int m0 = blockIdx.y * 128;
  const int z = blockIdx.z;
  float* part = z ? p1 : p0;

  const short* gsrc = (w < 2) ? attn : woh;
  short* lbuf = (w < 2) ? Ah : Wh;
  const int rbase = (w < 2) ? m0 : n0;
  const int jb = (w & 1) * 4;
  const int lrow = lane >> 2;
  const int gphys = lane & 3;

  f32x4 zero = {0.f, 0.f, 0.f, 0.f};
  f32x4 acc[4][4];
#pragma unroll
  for (int i = 0; i < 4; ++i)
#pragma unroll
    for (int j = 0; j < 4; ++j) acc[i][j] = zero;

  const int wm = w & 1, wn = w >> 1;

  for (int k0 = z * 512; k0 < z * 512 + 512; k0 += 32) {
    __syncthreads();
#pragma unroll
    for (int jj = 0; jj < 4; ++jj) {
      int j = jb + jj;
      int r = j * 16 + lrow;
      int gl = (gphys - (r >> 1)) & 3;
      gl_lds16(gsrc + (size_t)(rbase + r) * E_DIM + k0 + gl * 8, lbuf + j * 512);
    }
    __syncthreads();
    short8 ahf[4];
#pragma unroll
    for (int i = 0; i < 4; ++i) {
      int r = wm * 64 + i * 16 + l15;
      int idx = r * 32 + ((quad + (r >> 1)) & 3) * 8;
      ahf[i] = *(const short8*)&Ah[idx];
    }
#pragma unroll
    for (int j = 0; j < 4; ++j) {
      int r = wn * 64 + j * 16 + l15;
      int idx = r * 32 + ((quad + (r >> 1)) & 3) * 8;
      short8 bhf = *(const short8*)&Wh[idx];
#pragma unroll
      for (int i = 0; i < 4; ++i)
        acc[i][j] = __builtin_amdgcn_mfma_f32_16x16x32_f16(h8(ahf[i]), h8(bhf), acc[i][j], 0, 0, 0);
    }
  }

#pragma unroll
  for (int j = 0; j < 4; ++j) {
    const int gc = n0 + wn * 64 + j * 16 + l15;
#pragma unroll
    for (int i = 0; i < 4; ++i)
#pragma unroll
      for (int reg = 0; reg < 4; ++reg) {
        const int gm = m0 + wm * 64 + i * 16 + quad * 4 + reg;
        part[(size_t)gm * E_DIM + gc] = acc[i][j][reg];
      }
  }
}

// out = p0 + p1 + bias (broadcast over rows); float4 per thread
__global__ __launch_bounds__(256) void add_bias(
    const float* __restrict__ p0, const float* __restrict__ p1,
    const float* __restrict__ bo, float* __restrict__ out)
{
  const int i = blockIdx.x * 256 + threadIdx.x;      // float4 index
  const int col = (i * 4) & (E_DIM - 1);
  float4 a = ((const float4*)p0)[i];
  float4 b = ((const float4*)p1)[i];
  float4 c = *(const float4*)&bo[col];
  float4 o;
  o.x = a.x + b.x + c.x; o.y = a.y + b.y + c.y;
  o.z = a.z + b.z + c.z; o.w = a.w + b.w + c.w;
  ((float4*)out)[i] = o;
}

// ---------------------------------------------------------------------------
// Flash attention v4: barrier-free main loop (r6 structure) + LDS overlay:
// ring slot 2 overlays the Q region (Q is register-cached before slot 2's
// first write; one barrier after the qa load protects cross-wave Q reads).
// LDS 50 KB -> 3 blocks/CU (r6: 66 KB -> 2). O-reduce uses 32 KB scratch in
// 3 rounds (2 parallel half-payload writers each); w0 stores d01, w2 d23.
// ---------------------------------------------------------------------------
__global__ __launch_bounds__(256, 3) void attn_mfma(
    const short* __restrict__ q, const short* __restrict__ k,
    const short* __restrict__ vt, short* __restrict__ attn)
{
  __shared__ __align__(16) short SMEM[24576];   // 48 KB: slot2|Q, slot0, slot1
  __shared__ float l_red[4][128];

  const int tid = threadIdx.x;
  const int lane = tid & 63;
  const int w = tid >> 6;
  const int quad = lane >> 4;
  const int l15 = lane & 15;
  const int bhid = blockIdx.y;
  const int b = bhid >> 4, h = bhid & 15;
  const int t0 = blockIdx.x * 128;

  const short* qb = q + (size_t)bhid * T_DIM * 64;
  const short* kb = k + (size_t)bhid * T_DIM * 64;
  const short* vb = vt + (size_t)bhid * 64 * T_DIM;

  const int lrow8 = lane >> 3;
  const int gph8 = lane & 7;
  short* Qs = SMEM;                        // 16 KB, dead after qa load
  const int ring_off[3] = {8192, 16384, 0};  // chunk c -> SMEM + ring_off[c%3]

  // ---- stage Q tile [128][64] ----
#pragma unroll
  for (int jj = 0; jj < 4; ++jj) {
    int j = w * 4 + jj;
    int r = j * 8 + lrow8;
    int gl = (gph8 - (r >> 1)) & 7;
    gl_lds16(qb + (size_t)(t0 + r) * 64 + gl * 8, Qs + j * 512);
  }

  // ---- stage K/V chunks 0,1 into slots 0,1 (wave-private slices) ----
  const int kg = (gph8 - lrow8) & 7;
  const int vd = lane >> 1, vh = lane & 1;
#pragma unroll
  for (int c0 = 0; c0 < 2; ++c0) {
    short* slot = SMEM + ring_off[c0] + w * 2048;
    const int sg = c0 * 64 + w * 16;
    gl_lds16(kb + (size_t)(sg + lrow8) * 64 + kg * 8, slot);
    gl_lds16(kb + (size_t)(sg + lrow8 + 8) * 64 + kg * 8, slot + 512);
    gl_lds16(vb + (size_t)vd * T_DIM + sg + vh * 8, slot + 1024);
    gl_lds16(vb + (size_t)(vd + 32) * T_DIM + sg + vh * 8, slot + 1536);
  }
  __syncthreads();   // Q + slots 0,1 visible

  // ---- register-cache Q B-fragments ----
  short8 qa[8][2];
#pragma unroll
  for (int qbk = 0; qbk < 8; ++qbk)
#pragma unroll
    for (int st = 0; st < 2; ++st) {
      int r = qbk * 16 + l15;
      int idx = r * 64 + (((st * 4 + quad) + (r >> 1)) & 7) * 8;
      qa[qbk][st] = *(const short8*)&Qs[idx];
    }
  __syncthreads();   // all waves done reading Q before slot2 writes begin

  f32x4 zero = {0.f, 0.f, 0.f, 0.f};
  f32x4 acc[4][8];               // [dblk][qbk] : O^T partial over own s-subset
  float l_part[8];
#pragma unroll
  for (int d = 0; d < 4; ++d)
#pragma unroll
    for (int qb2 = 0; qb2 < 8; ++qb2) acc[d][qb2] = zero;
#pragma unroll
  for (int i = 0; i < 8; ++i) l_part[i] = 0.f;

  for (int c = 0; c < 32; ++c) {
    if (c >= 2) {
      if (c == 31) __builtin_amdgcn_s_waitcnt(0x0F70);   // vmcnt(0)
      else         __builtin_amdgcn_s_waitcnt(0x0F74);   // vmcnt(4)
    }
    const short* slot = SMEM + ring_off[c % 3] + w * 2048;

    short8 kf[2];
#pragma unroll
    for (int st = 0; st < 2; ++st)
      kf[st] = *(const short8*)&slot[l15 * 64 + (((st * 4 + quad) + l15) & 7) * 8];
    uint2 vfu[4];
#pragma unroll
    for (int dblk = 0; dblk < 4; ++dblk)
      vfu[dblk] = *(const uint2*)&slot[1024 + (dblk * 16 + l15) * 16 + quad * 4];

    if (c < 30) {
      short* nslot = SMEM + ring_off[(c + 2) % 3] + w * 2048;
      const int sg = (c + 2) * 64 + w * 16;
      gl_lds16(kb + (size_t)(sg + lrow8) * 64 + kg * 8, nslot);
      gl_lds16(kb + (size_t)(sg + lrow8 + 8) * 64 + kg * 8, nslot + 512);
      gl_lds16(vb + (size_t)vd * T_DIM + sg + vh * 8, nslot + 1024);
      gl_lds16(vb + (size_t)(vd + 32) * T_DIM + sg + vh * 8, nslot + 1536);
    }

    uint2 pb[8];
#pragma unroll
    for (int qbk = 0; qbk < 8; ++qbk) {
      f32x4 s = zero;
      s = __builtin_amdgcn_mfma_f32_16x16x32_f16(h8(kf[0]), h8(qa[qbk][0]), s, 0, 0, 0);
      s = __builtin_amdgcn_mfma_f32_16x16x32_f16(h8(kf[1]), h8(qa[qbk][1]), s, 0, 0, 0);
      float p0 = __builtin_amdgcn_exp2f(s[0]);
      float p1 = __builtin_amdgcn_exp2f(s[1]);
      float p2 = __builtin_amdgcn_exp2f(s[2]);
      float p3 = __builtin_amdgcn_exp2f(s[3]);
      l_part[qbk] += (p0 + p1) + (p2 + p3);
      pb[qbk].x = pk2(p0, p1);
      pb[qbk].y = pk2(p2, p3);
    }

#pragma unroll
    for (int dblk = 0; dblk < 4; ++dblk) {
      half4 va = __builtin_bit_cast(half4, vfu[dblk]);
#pragma unroll
      for (int qbk = 0; qbk < 8; ++qbk)
        acc[dblk][qbk] = __builtin_amdgcn_mfma_f32_16x16x16f16(
            va, __builtin_bit_cast(half4, pb[qbk]), acc[dblk][qbk], 0, 0, 0);
    }
  }

  // ---- l reduce over quads, publish per-wave ----
#pragma unroll
  for (int qbk = 0; qbk < 8; ++qbk) {
    float l = l_part[qbk];
    l += __shfl_xor(l, 16);
    l += __shfl_xor(l, 32);
    if (quad == 0) l_red[w][qbk * 16 + l15] = l;
  }
  __syncthreads();   // loop + l publish complete; SMEM reusable

  // ---- O reduce: 3 rounds x (2 half-payload writers), 32 KB scratch ----
  f32x4* R0 = (f32x4*)SMEM;          // 16 KB (dblk 0,1)
  f32x4* R1 = R0 + 1024;             // 16 KB (dblk 2,3)
  const int w01[3] = {1, 2, 3};      // d01 writers (to w0)
  const int w23[3] = {3, 0, 1};      // d23 writers (to w2)
#pragma unroll
  for (int rnd = 0; rnd < 3; ++rnd) {
    if (w == w01[rnd]) {
#pragma unroll
      for (int d2 = 0; d2 < 2; ++d2)
#pragma unroll
        for (int qbk = 0; qbk < 8; ++qbk)
          R0[(d2 * 8 + qbk) * 64 + lane] = acc[d2][qbk];
    }
    if (w == w23[rnd]) {
#pragma unroll
      for (int d2 = 0; d2 < 2; ++d2)
#pragma unroll
        for (int qbk = 0; qbk < 8; ++qbk)
          R1[(d2 * 8 + qbk) * 64 + lane] = acc[2 + d2][qbk];
    }
    __syncthreads();
    if (w == 0) {
#pragma unroll
      for (int d2 = 0; d2 < 2; ++d2)
#pragma unroll
        for (int qbk = 0; qbk < 8; ++qbk) {
          f32x4 t = R0[(d2 * 8 + qbk) * 64 + lane];
          acc[d2][qbk][0] += t[0]; acc[d2][qbk][1] += t[1];
          acc[d2][qbk][2] += t[2]; acc[d2][qbk][3] += t[3];
        }
    }
    if (w == 2) {
#pragma unroll
      for (int d2 = 0; d2 < 2; ++d2)
#pragma unroll
        for (int qbk = 0; qbk < 8; ++qbk) {
          f32x4 t = R1[(d2 * 8 + qbk) * 64 + lane];
          acc[2 + d2][qbk][0] += t[0]; acc[2 + d2][qbk][1] += t[1];
          acc[2 + d2][qbk][2] += t[2]; acc[2 + d2][qbk][3] += t[3];
        }
    }
    __syncthreads();
  }

  // ---- store: w0 -> dblk 0,1 ; w2 -> dblk 2,3 ----
  if (w == 0 || w == 2) {
#pragma unroll
    for (int qbk = 0; qbk < 8; ++qbk) {
      const int qq = qbk * 16 + l15;
      const float lsum = l_red[0][qq] + l_red[1][qq] + l_red[2][qq] + l_red[3][qq];
      const float inv = 1.f / lsum;
      const int t = t0 + qq;
      const size_t mrow = (size_t)(t * 2 + b) * E_DIM;
#pragma unroll
      for (int d2 = 0; d2 < 2; ++d2) {
        const int dblk = w + d2;       // w=0 -> 0,1 ; w=2 -> 2,3
        uint2 ov;
        ov.x = pk2(acc[dblk][qbk][0] * inv, acc[dblk][qbk][1] * inv);
        ov.y = pk2(acc[dblk][qbk][2] * inv, acc[dblk][qbk][3] * inv);
        *(uint2*)&attn[mrow + h * 64 + dblk * 16 + quad * 4] = ov;
      }
    }
  }
}

// ---------------------------------------------------------------------------
extern "C" void kernel_launch(void* const* d_in, const int* in_sizes, int n_in,
                              void* d_out, int out_size, void* d_ws, size_t ws_size,
                              hipStream_t stream)
{
  const float* x  = (const float*)d_in[0];
  const float* wq = (const float*)d_in[1];
  const float* bq = (const float*)d_in[2];
  const float* wk = (const float*)d_in[3];
  const float* bk = (const float*)d_in[4];
  const float* wv = (const float*)d_in[5];
  const float* bv = (const float*)d_in[6];
  const float* wo = (const float*)d_in[7];
  const float* bo = (const float*)d_in[8];
  float* out = (float*)d_out;

  short* ws = (short*)d_ws;
  const size_t M4 = (size_t)M_DIM * E_DIM;   // 4M elems
  const size_t M1 = (size_t)E_DIM * E_DIM;   // 1M elems
  // layout: live-late buffers first, dead-early ones later so fp32 split-K
  // partials can overlay them.
  short* aws  = ws;          // attn out fp16, live until gemm_out
  short* woh  = aws + M4;    // wo fp16, live until gemm_out
  short* xh   = woh + M1;    // dead after gemm_qkv
  short* wqh  = xh + M4;
  short* wkh  = wqh + M1;
  short* wvh  = wkh + M1;
  short* qws  = wvh + M1;    // dead after attn
  short* kws  = qws + M4;
  short* vtws = kws + M4;    // end = 24M shorts = 48 MB
  float* part0 = (float*)xh;           // 16 MB, overlays xh..qws (dead)
  float* part1 = part0 + M4;           // 16 MB, overlays qws..vtws (dead)

  convert_all<<<8192, 256, 0, stream>>>(x, wq, wk, wv, wo, xh, wqh, wkh, wvh, woh);
  gemm_qkv<<<dim3(24, 32), 256, 0, stream>>>(xh, wqh, wkh, wvh, bq, bk, bv,
                                             qws, kws, vtws);
  attn_mfma<<<dim3(16, 32), 256, 0, stream>>>(qws, kws, vtws, aws);
  gemm_out<<<dim3(8, 32, 2), 256, 0, stream>>>(aws, woh, part0, part1);
  add_bias<<<4096, 256, 0, stream>>>(part0, part1, bo, out);
}

// Round 8
// 234.235 us; speedup vs baseline: 1.8787x; 1.8787x over previous
//
#include <hip/hip_runtime.h>
#include <cstddef>
#include <cstdint>

#define T_DIM 2048
#define E_DIM 1024
#define M_DIM 4096   // T*B rows, row index = t*2 + b

typedef __attribute__((ext_vector_type(8))) short short8;      // 8 fp16 bit-patterns
typedef __attribute__((ext_vector_type(8))) _Float16 half8;    // mfma f16 A/B (x32)
typedef __attribute__((ext_vector_type(4))) _Float16 half4;    // mfma f16 A/B (x16)
typedef __attribute__((ext_vector_type(4))) float f32x4;       // mfma C/D

__device__ __forceinline__ short f16_bits(float v) {
  return __builtin_bit_cast(short, (_Float16)v);
}
__device__ __forceinline__ unsigned int pk2(float a, float b) {
  return __builtin_bit_cast(unsigned int, __builtin_amdgcn_cvt_pkrtz(a, b));
}
__device__ __forceinline__ half8 h8(short8 s) { return __builtin_bit_cast(half8, s); }

// async global->LDS, 16B per lane; LDS dest = wave-uniform base + lane*16
__device__ __forceinline__ void gl_lds16(const short* g, const short* l) {
  __builtin_amdgcn_global_load_lds(
      (const __attribute__((address_space(1))) unsigned int*)g,
      (__attribute__((address_space(3))) unsigned int*)l, 16, 0, 0);
}

// ---------------------------------------------------------------------------
// fp32 -> fp16 (RNE). blocks: [0,4096) x ; then 1024 each wq, wk, wv, wo.
// ---------------------------------------------------------------------------
__global__ __launch_bounds__(256) void convert_all(
    const float* __restrict__ x, const float* __restrict__ wq,
    const float* __restrict__ wk, const float* __restrict__ wv,
    const float* __restrict__ wo,
    short* __restrict__ xh, short* __restrict__ wqh, short* __restrict__ wkh,
    short* __restrict__ wvh, short* __restrict__ woh)
{
  const int bid = blockIdx.x;
  const float* in; short* hi; int base;
  if (bid < 4096)      { in = x;  hi = xh;  base = 0;    }
  else if (bid < 5120) { in = wq; hi = wqh; base = 4096; }
  else if (bid < 6144) { in = wk; hi = wkh; base = 5120; }
  else if (bid < 7168) { in = wv; hi = wvh; base = 6144; }
  else                 { in = wo; hi = woh; base = 7168; }
  const int i = (bid - base) * 256 + threadIdx.x;     // float4 index
  float4 v = ((const float4*)in)[i];
  uint2 p;
  p.x = (unsigned short)f16_bits(v.x) | ((unsigned int)(unsigned short)f16_bits(v.y) << 16);
  p.y = (unsigned short)f16_bits(v.z) | ((unsigned int)(unsigned short)f16_bits(v.w) << 16);
  ((uint2*)hi)[i] = p;
}

// ---------------------------------------------------------------------------
// Fused QKV GEMM, fp16 (verified r5). C = (A @ W^T + bias) * scale.
// ---------------------------------------------------------------------------
__global__ __launch_bounds__(256) void gemm_qkv(
    const short* __restrict__ xh,
    const short* __restrict__ wqh, const short* __restrict__ wkh,
    const short* __restrict__ wvh,
    const float* __restrict__ bq, const float* __restrict__ bk,
    const float* __restrict__ bv,
    short* __restrict__ qo, short* __restrict__ ko, short* __restrict__ vto)
{
  __shared__ __align__(16) short smem[128 * 32 * 2];   // Ah | Wh ; reused as Tb
  short* Ah = smem;
  short* Wh = smem + 128 * 32;
  const int tid = threadIdx.x;
  const int lane = tid & 63;
  const int w = tid >> 6;
  const int quad = lane >> 4;
  const int l15 = lane & 15;
  const int sel = blockIdx.x >> 3;
  const int n0 = (blockIdx.x & 7) * 128;
  const int m0 = blockIdx.y * 128;

  const short* wsel = sel == 0 ? wqh : sel == 1 ? wkh : wvh;
  const float* bias = sel == 0 ? bq : sel == 1 ? bk : bv;
  const float scale = sel == 0 ? 0.125f * 1.44269504088896f : 1.0f;

  const short* gsrc = (w < 2) ? xh : wsel;
  short* lbuf = (w < 2) ? Ah : Wh;
  const int rbase = (w < 2) ? m0 : n0;
  const int jb = (w & 1) * 4;
  const int lrow = lane >> 2;
  const int gphys = lane & 3;

  f32x4 zero = {0.f, 0.f, 0.f, 0.f};
  f32x4 acc[4][4];
#pragma unroll
  for (int i = 0; i < 4; ++i)
#pragma unroll
    for (int j = 0; j < 4; ++j) acc[i][j] = zero;

  const int wm = w & 1, wn = w >> 1;

  for (int k0 = 0; k0 < E_DIM; k0 += 32) {
    __syncthreads();
#pragma unroll
    for (int jj = 0; jj < 4; ++jj) {
      int j = jb + jj;
      int r = j * 16 + lrow;
      int gl = (gphys - (r >> 1)) & 3;
      gl_lds16(gsrc + (size_t)(rbase + r) * E_DIM + k0 + gl * 8, lbuf + j * 512);
    }
    __syncthreads();
    short8 ahf[4];
#pragma unroll
    for (int i = 0; i < 4; ++i) {
      int r = wm * 64 + i * 16 + l15;
      int idx = r * 32 + ((quad + (r >> 1)) & 3) * 8;
      ahf[i] = *(const short8*)&Ah[idx];
    }
#pragma unroll
    for (int j = 0; j < 4; ++j) {
      int r = wn * 64 + j * 16 + l15;
      int idx = r * 32 + ((quad + (r >> 1)) & 3) * 8;
      short8 bhf = *(const short8*)&Wh[idx];
#pragma unroll
      for (int i = 0; i < 4; ++i)
        acc[i][j] = __builtin_amdgcn_mfma_f32_16x16x32_f16(h8(ahf[i]), h8(bhf), acc[i][j], 0, 0, 0);
    }
  }

  if (sel < 2) {
#pragma unroll
    for (int j = 0; j < 4; ++j) {
      const int gc = n0 + wn * 64 + j * 16 + l15;
      const float bb = bias[gc];
      const int h = gc >> 6, d = gc & 63;
      short* dst = sel == 0 ? qo : ko;
#pragma unroll
      for (int i = 0; i < 4; ++i)
#pragma unroll
        for (int reg = 0; reg < 4; ++reg) {
          const int gm = m0 + wm * 64 + i * 16 + quad * 4 + reg;
          const float val = (acc[i][j][reg] + bb) * scale;
          const int t = gm >> 1, b = gm & 1;
          dst[((size_t)(b * 16 + h) * T_DIM + t) * 64 + d] = f16_bits(val);
        }
    }
  } else {
    short* Tb = smem;   // 64 * 128 * 2B = 16KB
    const int by = blockIdx.y;
#pragma unroll
    for (int R = 0; R < 2; ++R) {
      __syncthreads();
      if (wn == R) {
#pragma unroll
        for (int j = 0; j < 4; ++j) {
          const int nl = j * 16 + l15;
          const int gc = n0 + R * 64 + nl;
          const float bb = bias[gc];
#pragma unroll
          for (int i = 0; i < 4; ++i) {
            const int tp = wm * 32 + i * 8 + quad * 2;
            unsigned int lo = pk2(acc[i][j][0] + bb, acc[i][j][2] + bb);
            unsigned int hi = pk2(acc[i][j][1] + bb, acc[i][j][3] + bb);
            const int g0 = tp >> 3;
            const int sub = tp & 7;
            *(unsigned int*)&Tb[nl * 128 + ((g0 + nl) & 15) * 8 + sub] = lo;
            *(unsigned int*)&Tb[nl * 128 + ((g0 + 8 + nl) & 15) * 8 + sub] = hi;
          }
        }
      }
      __syncthreads();
#pragma unroll
      for (int ii = 0; ii < 4; ++ii) {
        const int n = w * 16 + ii * 4 + quad;
        const int g = (l15 - n) & 15;
        short8 vvec = *(const short8*)&Tb[n * 128 + l15 * 8];
        const int gc = n0 + R * 64 + n;
        const int h = gc >> 6, d = gc & 63;
        const int b = g >> 3;
        const int t = by * 64 + (g & 7) * 8;
        *(short8*)&vto[((size_t)(b * 16 + h) * 64 + d) * T_DIM + t] = vvec;
      }
    }
  }
}

// ---------------------------------------------------------------------------
// Output projection GEMM, split-K=2: partial = attn @ wo^T over K half.
// Grid (8,32,2) -> 512 blocks = 2/CU.
// ---------------------------------------------------------------------------
__global__ __launch_bounds__(256) void gemm_out(
    const short* __restrict__ attn, const short* __restrict__ woh,
    float* __restrict__ p0, float* __restrict__ p1)
{
  __shared__ __align__(16) short Ah[128 * 32], Wh[128 * 32];
  const int tid = threadIdx.x;
  const int lane = tid & 63;
  const int w = tid >> 6;
  const int quad = lane >> 4;
  const int l15 = lane & 15;
  const int n0 = blockIdx.x * 128;
  const int m0 = blockIdx.y * 128;
  const int z = blockIdx.z;
  float* part = z ? p1 : p0;

  const short* gsrc = (w < 2) ? attn : woh;
  short* lbuf = (w < 2) ? Ah : Wh;
  const int rbase = (w < 2) ? m0 : n0;
  const int jb = (w & 1) * 4;
  const int lrow = lane >> 2;
  const int gphys = lane & 3;

  f32x4 zero = {0.f, 0.f, 0.f, 0.f};
  f32x4 acc[4][4];
#pragma unroll
  for (int i = 0; i < 4; ++i)
#pragma unroll
    for (int j = 0; j < 4; ++j) acc[i][j] = zero;

  const int wm = w & 1, wn = w >> 1;

  for (int k0 = z * 512; k0 < z * 512 + 512; k0 += 32) {
    __syncthreads();
#pragma unroll
    for (int jj = 0; jj < 4; ++jj) {
      int j = jb + jj;
      int r = j * 16 + lrow;
      int gl = (gphys - (r >> 1)) & 3;
      gl_lds16(gsrc + (size_t)(rbase + r) * E_DIM + k0 + gl * 8, lbuf + j * 512);
    }
    __syncthreads();
    short8 ahf[4];
#pragma unroll
    for (int i = 0; i < 4; ++i) {
      int r = wm * 64 + i * 16 + l15;
      int idx = r * 32 + ((quad + (r >> 1)) & 3) * 8;
      ahf[i] = *(const short8*)&Ah[idx];
    }
#pragma unroll
    for (int j = 0; j < 4; ++j) {
      int r = wn * 64 + j * 16 + l15;
      int idx = r * 32 + ((quad + (r >> 1)) & 3) * 8;
      short8 bhf = *(const short8*)&Wh[idx];
#pragma unroll
      for (int i = 0; i < 4; ++i)
        acc[i][j] = __builtin_amdgcn_mfma_f32_16x16x32_f16(h8(ahf[i]), h8(bhf), acc[i][j], 0, 0, 0);
    }
  }

#pragma unroll
  for (int j = 0; j < 4; ++j) {
    const int gc = n0 + wn * 64 + j * 16 + l15;
#pragma unroll
    for (int i = 0; i < 4; ++i)
#pragma unroll
      for (int reg = 0; reg < 4; ++reg) {
        const int gm = m0 + wm * 64 + i * 16 + quad * 4 + reg;
        part[(size_t)gm * E_DIM + gc] = acc[i][j][reg];
      }
  }
}

// out = p0 + p1 + bias (broadcast over rows); float4 per thread
__global__ __launch_bounds__(256) void add_bias(
    const float* __restrict__ p0, const float* __restrict__ p1,
    const float* __restrict__ bo, float* __restrict__ out)
{
  const int i = blockIdx.x * 256 + threadIdx.x;      // float4 index
  const int col = (i * 4) & (E_DIM - 1);
  float4 a = ((const float4*)p0)[i];
  float4 b = ((const float4*)p1)[i];
  float4 c = *(const float4*)&bo[col];
  float4 o;
  o.x = a.x + b.x + c.x; o.y = a.y + b.y + c.y;
  o.z = a.z + b.z + c.z; o.w = a.w + b.w + c.w;
  ((float4*)out)[i] = o;
}

// ---------------------------------------------------------------------------
// Flash attention v4b: r6's barrier-free main loop + 50 KB LDS overlay, with
// __launch_bounds__(256,2). r7's (256,3) capped VGPRs at ~170 < the ~200
// this kernel needs live (acc 128 + qa 32 + frags) -> accumulator spills in
// the hot loop -> 1.2 GB/dispatch scratch traffic, 285 us. Register budget
// is the binding constraint; occupancy stays 2 blocks/CU (8 waves).
// ---------------------------------------------------------------------------
__global__ __launch_bounds__(256, 2) void attn_mfma(
    const short* __restrict__ q, const short* __restrict__ k,
    const short* __restrict__ vt, short* __restrict__ attn)
{
  __shared__ __align__(16) short SMEM[24576];   // 48 KB: slot2|Q, slot0, slot1
  __shared__ float l_red[4][128];

  const int tid = threadIdx.x;
  const int lane = tid & 63;
  const int w = tid >> 6;
  const int quad = lane >> 4;
  const int l15 = lane & 15;
  const int bhid = blockIdx.y;
  const int b = bhid >> 4, h = bhid & 15;
  const int t0 = blockIdx.x * 128;

  const short* qb = q + (size_t)bhid * T_DIM * 64;
  const short* kb = k + (size_t)bhid * T_DIM * 64;
  const short* vb = vt + (size_t)bhid * 64 * T_DIM;

  const int lrow8 = lane >> 3;
  const int gph8 = lane & 7;
  short* Qs = SMEM;                        // 16 KB, dead after qa load
  const int ring_off[3] = {8192, 16384, 0};  // chunk c -> SMEM + ring_off[c%3]

  // ---- stage Q tile [128][64] ----
#pragma unroll
  for (int jj = 0; jj < 4; ++jj) {
    int j = w * 4 + jj;
    int r = j * 8 + lrow8;
    int gl = (gph8 - (r >> 1)) & 7;
    gl_lds16(qb + (size_t)(t0 + r) * 64 + gl * 8, Qs + j * 512);
  }

  // ---- stage K/V chunks 0,1 into slots 0,1 (wave-private slices) ----
  const int kg = (gph8 - lrow8) & 7;
  const int vd = lane >> 1, vh = lane & 1;
#pragma unroll
  for (int c0 = 0; c0 < 2; ++c0) {
    short* slot = SMEM + ring_off[c0] + w * 2048;
    const int sg = c0 * 64 + w * 16;
    gl_lds16(kb + (size_t)(sg + lrow8) * 64 + kg * 8, slot);
    gl_lds16(kb + (size_t)(sg + lrow8 + 8) * 64 + kg * 8, slot + 512);
    gl_lds16(vb + (size_t)vd * T_DIM + sg + vh * 8, slot + 1024);
    gl_lds16(vb + (size_t)(vd + 32) * T_DIM + sg + vh * 8, slot + 1536);
  }
  __syncthreads();   // Q + slots 0,1 visible

  // ---- register-cache Q B-fragments ----
  short8 qa[8][2];
#pragma unroll
  for (int qbk = 0; qbk < 8; ++qbk)
#pragma unroll
    for (int st = 0; st < 2; ++st) {
      int r = qbk * 16 + l15;
      int idx = r * 64 + (((st * 4 + quad) + (r >> 1)) & 7) * 8;
      qa[qbk][st] = *(const short8*)&Qs[idx];
    }
  __syncthreads();   // all waves done reading Q before slot2 writes begin

  f32x4 zero = {0.f, 0.f, 0.f, 0.f};
  f32x4 acc[4][8];               // [dblk][qbk] : O^T partial over own s-subset
  float l_part[8];
#pragma unroll
  for (int d = 0; d < 4; ++d)
#pragma unroll
    for (int qb2 = 0; qb2 < 8; ++qb2) acc[d][qb2] = zero;
#pragma unroll
  for (int i = 0; i < 8; ++i) l_part[i] = 0.f;

  for (int c = 0; c < 32; ++c) {
    if (c >= 2) {
      if (c == 31) __builtin_amdgcn_s_waitcnt(0x0F70);   // vmcnt(0)
      else         __builtin_amdgcn_s_waitcnt(0x0F74);   // vmcnt(4)
    }
    const short* slot = SMEM + ring_off[c % 3] + w * 2048;

    short8 kf[2];
#pragma unroll
    for (int st = 0; st < 2; ++st)
      kf[st] = *(const short8*)&slot[l15 * 64 + (((st * 4 + quad) + l15) & 7) * 8];
    uint2 vfu[4];
#pragma unroll
    for (int dblk = 0; dblk < 4; ++dblk)
      vfu[dblk] = *(const uint2*)&slot[1024 + (dblk * 16 + l15) * 16 + quad * 4];

    if (c < 30) {
      short* nslot = SMEM + ring_off[(c + 2) % 3] + w * 2048;
      const int sg = (c + 2) * 64 + w * 16;
      gl_lds16(kb + (size_t)(sg + lrow8) * 64 + kg * 8, nslot);
      gl_lds16(kb + (size_t)(sg + lrow8 + 8) * 64 + kg * 8, nslot + 512);
      gl_lds16(vb + (size_t)vd * T_DIM + sg + vh * 8, nslot + 1024);
      gl_lds16(vb + (size_t)(vd + 32) * T_DIM + sg + vh * 8, nslot + 1536);
    }

    uint2 pb[8];
#pragma unroll
    for (int qbk = 0; qbk < 8; ++qbk) {
      f32x4 s = zero;
      s = __builtin_amdgcn_mfma_f32_16x16x32_f16(h8(kf[0]), h8(qa[qbk][0]), s, 0, 0, 0);
      s = __builtin_amdgcn_mfma_f32_16x16x32_f16(h8(kf[1]), h8(qa[qbk][1]), s, 0, 0, 0);
      float p0 = __builtin_amdgcn_exp2f(s[0]);
      float p1 = __builtin_amdgcn_exp2f(s[1]);
      float p2 = __builtin_amdgcn_exp2f(s[2]);
      float p3 = __builtin_amdgcn_exp2f(s[3]);
      l_part[qbk] += (p0 + p1) + (p2 + p3);
      pb[qbk].x = pk2(p0, p1);
      pb[qbk].y = pk2(p2, p3);
    }

#pragma unroll
    for (int dblk = 0; dblk < 4; ++dblk) {
      half4 va = __builtin_bit_cast(half4, vfu[dblk]);
#pragma unroll
      for (int qbk = 0; qbk < 8; ++qbk)
        acc[dblk][qbk] = __builtin_amdgcn_mfma_f32_16x16x16f16(
            va, __builtin_bit_cast(half4, pb[qbk]), acc[dblk][qbk], 0, 0, 0);
    }
  }

  // ---- l reduce over quads, publish per-wave ----
#pragma unroll
  for (int qbk = 0; qbk < 8; ++qbk) {
    float l = l_part[qbk];
    l += __shfl_xor(l, 16);
    l += __shfl_xor(l, 32);
    if (quad == 0) l_red[w][qbk * 16 + l15] = l;
  }
  __syncthreads();   // loop + l publish complete; SMEM reusable

  // ---- O reduce: 3 rounds x (2 half-payload writers), 32 KB scratch ----
  f32x4* R0 = (f32x4*)SMEM;          // 16 KB (dblk 0,1)
  f32x4* R1 = R0 + 1024;             // 16 KB (dblk 2,3)
  const int w01[3] = {1, 2, 3};      // d01 writers (to w0)
  const int w23[3] = {3, 0, 1};      // d23 writers (to w2)
#pragma unroll
  for (int rnd = 0; rnd < 3; ++rnd) {
    if (w == w01[rnd]) {
#pragma unroll
      for (int d2 = 0; d2 < 2; ++d2)
#pragma unroll
        for (int qbk = 0; qbk < 8; ++qbk)
          R0[(d2 * 8 + qbk) * 64 + lane] = acc[d2][qbk];
    }
    if (w == w23[rnd]) {
#pragma unroll
      for (int d2 = 0; d2 < 2; ++d2)
#pragma unroll
        for (int qbk = 0; qbk < 8; ++qbk)
          R1[(d2 * 8 + qbk) * 64 + lane] = acc[2 + d2][qbk];
    }
    __syncthreads();
    if (w == 0) {
#pragma unroll
      for (int d2 = 0; d2 < 2; ++d2)
#pragma unroll
        for (int qbk = 0; qbk < 8; ++qbk) {
          f32x4 t = R0[(d2 * 8 + qbk) * 64 + lane];
          acc[d2][qbk][0] += t[0]; acc[d2][qbk][1] += t[1];
          acc[d2][qbk][2] += t[2]; acc[d2][qbk][3] += t[3];
        }
    }
    if (w == 2) {
#pragma unroll
      for (int d2 = 0; d2 < 2; ++d2)
#pragma unroll
        for (int qbk = 0; qbk < 8; ++qbk) {
          f32x4 t = R1[(d2 * 8 + qbk) * 64 + lane];
          acc[2 + d2][qbk][0] += t[0]; acc[2 + d2][qbk][1] += t[1];
          acc[2 + d2][qbk][2] += t[2]; acc[2 + d2][qbk][3] += t[3];
        }
    }
    __syncthreads();
  }

  // ---- store: w0 -> dblk 0,1 ; w2 -> dblk 2,3 ----
  if (w == 0 || w == 2) {
#pragma unroll
    for (int qbk = 0; qbk < 8; ++qbk) {
      const int qq = qbk * 16 + l15;
      const float lsum = l_red[0][qq] + l_red[1][qq] + l_red[2][qq] + l_red[3][qq];
      const float inv = 1.f / lsum;
      const int t = t0 + qq;
      const size_t mrow = (size_t)(t * 2 + b) * E_DIM;
#pragma unroll
      for (int d2 = 0; d2 < 2; ++d2) {
        const int dblk = w + d2;       // w=0 -> 0,1 ; w=2 -> 2,3
        uint2 ov;
        ov.x = pk2(acc[dblk][qbk][0] * inv, acc[dblk][qbk][1] * inv);
        ov.y = pk2(acc[dblk][qbk][2] * inv, acc[dblk][qbk][3] * inv);
        *(uint2*)&attn[mrow + h * 64 + dblk * 16 + quad * 4] = ov;
      }
    }
  }
}

// ---------------------------------------------------------------------------
extern "C" void kernel_launch(void* const* d_in, const int* in_sizes, int n_in,
                              void* d_out, int out_size, void* d_ws, size_t ws_size,
                              hipStream_t stream)
{
  const float* x  = (const float*)d_in[0];
  const float* wq = (const float*)d_in[1];
  const float* bq = (const float*)d_in[2];
  const float* wk = (const float*)d_in[3];
  const float* bk = (const float*)d_in[4];
  const float* wv = (const float*)d_in[5];
  const float* bv = (const float*)d_in[6];
  const float* wo = (const float*)d_in[7];
  const float* bo = (const float*)d_in[8];
  float* out = (float*)d_out;

  short* ws = (short*)d_ws;
  const size_t M4 = (size_t)M_DIM * E_DIM;   // 4M elems
  const size_t M1 = (size_t)E_DIM * E_DIM;   // 1M elems
  // layout: live-late buffers first, dead-early ones later so fp32 split-K
  // partials can overlay them.
  short* aws  = ws;          // attn out fp16, live until gemm_out
  short* woh  = aws + M4;    // wo fp16, live until gemm_out
  short* xh   = woh + M1;    // dead after gemm_qkv
  short* wqh  = xh + M4;
  short* wkh  = wqh + M1;
  short* wvh  = wkh + M1;
  short* qws  = wvh + M1;    // dead after attn
  short* kws  = qws + M4;
  short* vtws = kws + M4;    // end = 24M shorts = 48 MB
  float* part0 = (float*)xh;           // 16 MB, overlays xh..qws (dead)
  float* part1 = part0 + M4;           // 16 MB, overlays qws..vtws (dead)

  convert_all<<<8192, 256, 0, stream>>>(x, wq, wk, wv, wo, xh, wqh, wkh, wvh, woh);
  gemm_qkv<<<dim3(24, 32), 256, 0, stream>>>(xh, wqh, wkh, wvh, bq, bk, bv,
                                             qws, kws, vtws);
  attn_mfma<<<dim3(16, 32), 256, 0, stream>>>(qws, kws, vtws, aws);
  gemm_out<<<dim3(8, 32, 2), 256, 0, stream>>>(aws, woh, part0, part1);
  add_bias<<<4096, 256, 0, stream>>>(part0, part1, bo, out);
}

// Round 9
// 204.050 us; speedup vs baseline: 2.1566x; 1.1479x over previous
//
#include <hip/hip_runtime.h>
#include <cstddef>
#include <cstdint>

#define T_DIM 2048
#define E_DIM 1024
#define M_DIM 4096   // T*B rows, row index = t*2 + b

typedef __attribute__((ext_vector_type(8))) short short8;      // 8 fp16 bit-patterns
typedef __attribute__((ext_vector_type(8))) _Float16 half8;    // mfma f16 A/B (x32)
typedef __attribute__((ext_vector_type(4))) _Float16 half4;    // mfma f16 A/B (x16)
typedef __attribute__((ext_vector_type(4))) float f32x4;       // mfma C/D

__device__ __forceinline__ short f16_bits(float v) {
  return __builtin_bit_cast(short, (_Float16)v);
}
__device__ __forceinline__ unsigned int pk2(float a, float b) {
  return __builtin_bit_cast(unsigned int, __builtin_amdgcn_cvt_pkrtz(a, b));
}
__device__ __forceinline__ half8 h8(short8 s) { return __builtin_bit_cast(half8, s); }

// async global->LDS, 16B per lane; LDS dest = wave-uniform base + lane*16
__device__ __forceinline__ void gl_lds16(const short* g, const short* l) {
  __builtin_amdgcn_global_load_lds(
      (const __attribute__((address_space(1))) unsigned int*)g,
      (__attribute__((address_space(3))) unsigned int*)l, 16, 0, 0);
}

// ---------------------------------------------------------------------------
// fp32 -> fp16 (RNE). blocks: [0,4096) x ; then 1024 each wq, wk, wv, wo.
// ---------------------------------------------------------------------------
__global__ __launch_bounds__(256) void convert_all(
    const float* __restrict__ x, const float* __restrict__ wq,
    const float* __restrict__ wk, const float* __restrict__ wv,
    const float* __restrict__ wo,
    short* __restrict__ xh, short* __restrict__ wqh, short* __restrict__ wkh,
    short* __restrict__ wvh, short* __restrict__ woh)
{
  const int bid = blockIdx.x;
  const float* in; short* hi; int base;
  if (bid < 4096)      { in = x;  hi = xh;  base = 0;    }
  else if (bid < 5120) { in = wq; hi = wqh; base = 4096; }
  else if (bid < 6144) { in = wk; hi = wkh; base = 5120; }
  else if (bid < 7168) { in = wv; hi = wvh; base = 6144; }
  else                 { in = wo; hi = woh; base = 7168; }
  const int i = (bid - base) * 256 + threadIdx.x;     // float4 index
  float4 v = ((const float4*)in)[i];
  uint2 p;
  p.x = (unsigned short)f16_bits(v.x) | ((unsigned int)(unsigned short)f16_bits(v.y) << 16);
  p.y = (unsigned short)f16_bits(v.z) | ((unsigned int)(unsigned short)f16_bits(v.w) << 16);
  ((uint2*)hi)[i] = p;
}

// ---------------------------------------------------------------------------
// Fused QKV GEMM, fp16, BK=64 (half the barriers of the r5 BK=32 version;
// the per-iter vmcnt(0)+barrier drain is the m97 structural stall).
// C = (A @ W^T + bias) * scale. LDS 32 KB -> up to 4 blocks/CU.
// Staging swizzle: phys 16B-group p = (logical g + row) & 7 (attn-verified).
// ---------------------------------------------------------------------------
__global__ __launch_bounds__(256) void gemm_qkv(
    const short* __restrict__ xh,
    const short* __restrict__ wqh, const short* __restrict__ wkh,
    const short* __restrict__ wvh,
    const float* __restrict__ bq, const float* __restrict__ bk,
    const float* __restrict__ bv,
    short* __restrict__ qo, short* __restrict__ ko, short* __restrict__ vto)
{
  __shared__ __align__(16) short smem[128 * 64 * 2];   // Ah | Wh ; Tb overlays
  short* Ah = smem;
  short* Wh = smem + 8192;
  const int tid = threadIdx.x;
  const int lane = tid & 63;
  const int w = tid >> 6;
  const int quad = lane >> 4;
  const int l15 = lane & 15;
  const int sel = blockIdx.x >> 3;
  const int n0 = (blockIdx.x & 7) * 128;
  const int m0 = blockIdx.y * 128;

  const short* wsel = sel == 0 ? wqh : sel == 1 ? wkh : wvh;
  const float* bias = sel == 0 ? bq : sel == 1 ? bk : bv;
  const float scale = sel == 0 ? 0.125f * 1.44269504088896f : 1.0f;

  const short* gsrc = (w < 2) ? xh : wsel;
  short* lbuf = (w < 2) ? Ah : Wh;
  const int rbase = (w < 2) ? m0 : n0;
  const int lrow8 = lane >> 3;
  const int gph8 = lane & 7;
  const int kg = (gph8 - lrow8) & 7;    // global k-group this lane stages

  f32x4 zero = {0.f, 0.f, 0.f, 0.f};
  f32x4 acc[4][4];
#pragma unroll
  for (int i = 0; i < 4; ++i)
#pragma unroll
    for (int j = 0; j < 4; ++j) acc[i][j] = zero;

  const int wm = w & 1, wn = w >> 1;

  for (int k0 = 0; k0 < E_DIM; k0 += 64) {
    __syncthreads();
#pragma unroll
    for (int jj = 0; jj < 8; ++jj) {
      int j = (w & 1) * 8 + jj;       // 16 staging insts per matrix, 2 waves
      int r = j * 8 + lrow8;          // 0..127
      gl_lds16(gsrc + (size_t)(rbase + r) * E_DIM + k0 + kg * 8, lbuf + j * 512);
    }
    __syncthreads();
#pragma unroll
    for (int ks = 0; ks < 2; ++ks) {
      short8 ahf[4];
#pragma unroll
      for (int i = 0; i < 4; ++i) {
        int r = wm * 64 + i * 16 + l15;
        ahf[i] = *(const short8*)&Ah[r * 64 + ((ks * 4 + quad + r) & 7) * 8];
      }
#pragma unroll
      for (int j = 0; j < 4; ++j) {
        int r = wn * 64 + j * 16 + l15;
        short8 bhf = *(const short8*)&Wh[r * 64 + ((ks * 4 + quad + r) & 7) * 8];
#pragma unroll
        for (int i = 0; i < 4; ++i)
          acc[i][j] = __builtin_amdgcn_mfma_f32_16x16x32_f16(h8(ahf[i]), h8(bhf), acc[i][j], 0, 0, 0);
      }
    }
  }

  if (sel < 2) {
#pragma unroll
    for (int j = 0; j < 4; ++j) {
      const int gc = n0 + wn * 64 + j * 16 + l15;
      const float bb = bias[gc];
      const int h = gc >> 6, d = gc & 63;
      short* dst = sel == 0 ? qo : ko;
#pragma unroll
      for (int i = 0; i < 4; ++i)
#pragma unroll
        for (int reg = 0; reg < 4; ++reg) {
          const int gm = m0 + wm * 64 + i * 16 + quad * 4 + reg;
          const float val = (acc[i][j][reg] + bb) * scale;
          const int t = gm >> 1, b = gm & 1;
          dst[((size_t)(b * 16 + h) * T_DIM + t) * 64 + d] = f16_bits(val);
        }
    }
  } else {
    short* Tb = smem;   // 64 * 128 * 2B = 16KB (fits in the 32KB block)
    const int by = blockIdx.y;
#pragma unroll
    for (int R = 0; R < 2; ++R) {
      __syncthreads();
      if (wn == R) {
#pragma unroll
        for (int j = 0; j < 4; ++j) {
          const int nl = j * 16 + l15;
          const int gc = n0 + R * 64 + nl;
          const float bb = bias[gc];
#pragma unroll
          for (int i = 0; i < 4; ++i) {
            const int tp = wm * 32 + i * 8 + quad * 2;        // t' base (even)
            unsigned int lo = pk2(acc[i][j][0] + bb, acc[i][j][2] + bb);
            unsigned int hi = pk2(acc[i][j][1] + bb, acc[i][j][3] + bb);
            const int g0 = tp >> 3;
            const int sub = tp & 7;
            *(unsigned int*)&Tb[nl * 128 + ((g0 + nl) & 15) * 8 + sub] = lo;
            *(unsigned int*)&Tb[nl * 128 + ((g0 + 8 + nl) & 15) * 8 + sub] = hi;
          }
        }
      }
      __syncthreads();
#pragma unroll
      for (int ii = 0; ii < 4; ++ii) {
        const int n = w * 16 + ii * 4 + quad;
        const int g = (l15 - n) & 15;
        short8 vvec = *(const short8*)&Tb[n * 128 + l15 * 8];
        const int gc = n0 + R * 64 + n;
        const int h = gc >> 6, d = gc & 63;
        const int b = g >> 3;
        const int t = by * 64 + (g & 7) * 8;
        *(short8*)&vto[((size_t)(b * 16 + h) * 64 + d) * T_DIM + t] = vvec;
      }
    }
  }
}

// ---------------------------------------------------------------------------
// Output projection GEMM, split-K=2, BK=64. Grid (8,32,2) -> 512 blocks.
// ---------------------------------------------------------------------------
__global__ __launch_bounds__(256) void gemm_out(
    const short* __restrict__ attn, const short* __restrict__ woh,
    float* __restrict__ p0, float* __restrict__ p1)
{
  __shared__ __align__(16) short smem[128 * 64 * 2];
  short* Ah = smem;
  short* Wh = smem + 8192;
  const int tid = threadIdx.x;
  const int lane = tid & 63;
  const int w = tid >> 6;
  const int quad = lane >> 4;
  const int l15 = lane & 15;
  const int n0 = blockIdx.x * 128;
  const int m0 = blockIdx.y * 128;
  const int z = blockIdx.z;
  float* part = z ? p1 : p0;

  const short* gsrc = (w < 2) ? attn : woh;
  short* lbuf = (w < 2) ? Ah : Wh;
  const int rbase = (w < 2) ? m0 : n0;
  const int lrow8 = lane >> 3;
  const int gph8 = lane & 7;
  const int kg = (gph8 - lrow8) & 7;

  f32x4 zero = {0.f, 0.f, 0.f, 0.f};
  f32x4 acc[4][4];
#pragma unroll
  for (int i = 0; i < 4; ++i)
#pragma unroll
    for (int j = 0; j < 4; ++j) acc[i][j] = zero;

  const int wm = w & 1, wn = w >> 1;

  for (int k0 = z * 512; k0 < z * 512 + 512; k0 += 64) {
    __syncthreads();
#pragma unroll
    for (int jj = 0; jj < 8; ++jj) {
      int j = (w & 1) * 8 + jj;
      int r = j * 8 + lrow8;
      gl_lds16(gsrc + (size_t)(rbase + r) * E_DIM + k0 + kg * 8, lbuf + j * 512);
    }
    __syncthreads();
#pragma unroll
    for (int ks = 0; ks < 2; ++ks) {
      short8 ahf[4];
#pragma unroll
      for (int i = 0; i < 4; ++i) {
        int r = wm * 64 + i * 16 + l15;
        ahf[i] = *(const short8*)&Ah[r * 64 + ((ks * 4 + quad + r) & 7) * 8];
      }
#pragma unroll
      for (int j = 0; j < 4; ++j) {
        int r = wn * 64 + j * 16 + l15;
        short8 bhf = *(const short8*)&Wh[r * 64 + ((ks * 4 + quad + r) & 7) * 8];
#pragma unroll
        for (int i = 0; i < 4; ++i)
          acc[i][j] = __builtin_amdgcn_mfma_f32_16x16x32_f16(h8(ahf[i]), h8(bhf), acc[i][j], 0, 0, 0);
      }
    }
  }

#pragma unroll
  for (int j = 0; j < 4; ++j) {
    const int gc = n0 + wn * 64 + j * 16 + l15;
#pragma unroll
    for (int i = 0; i < 4; ++i)
#pragma unroll
      for (int reg = 0; reg < 4; ++reg) {
        const int gm = m0 + wm * 64 + i * 16 + quad * 4 + reg;
        part[(size_t)gm * E_DIM + gc] = acc[i][j][reg];
      }
  }
}

// out = p0 + p1 + bias (broadcast over rows); float4 per thread
__global__ __launch_bounds__(256) void add_bias(
    const float* __restrict__ p0, const float* __restrict__ p1,
    const float* __restrict__ bo, float* __restrict__ out)
{
  const int i = blockIdx.x * 256 + threadIdx.x;      // float4 index
  const int col = (i * 4) & (E_DIM - 1);
  float4 a = ((const float4*)p0)[i];
  float4 b = ((const float4*)p1)[i];
  float4 c = *(const float4*)&bo[col];
  float4 o;
  o.x = a.x + b.x + c.x; o.y = a.y + b.y + c.y;
  o.z = a.z + b.z + c.z; o.w = a.w + b.w + c.w;
  ((float4*)out)[i] = o;
}

// ---------------------------------------------------------------------------
// Flash attention v3 (EXACT r6 kernel — measured 52 us, WRITE 8 MB).
// Barrier-free main loop, wave-private s-slices, 3-deep K/V ring with
// arithmetic ring indexing (r7/r8's ring_off[] private array caused
// scratch spill: WRITE_SIZE 218 MB). launch_bounds(256,2): register budget
// is the binding constraint (~250 live VGPR+AGPR).
// ---------------------------------------------------------------------------
__global__ __launch_bounds__(256, 2) void attn_mfma(
    const short* __restrict__ q, const short* __restrict__ k,
    const short* __restrict__ vt, short* __restrict__ attn)
{
  __shared__ __align__(16) short SMEM[32768];   // 64 KB
  __shared__ float l_red[4][128];
  short* Qs = SMEM;            // 8192 shorts (16 KB), dead after qa load
  short* KV = SMEM + 8192;     // ring[3] x wave[4] x (K 1024 + V 1024 shorts)

  const int tid = threadIdx.x;
  const int lane = tid & 63;
  const int w = tid >> 6;
  const int quad = lane >> 4;
  const int l15 = lane & 15;
  const int bhid = blockIdx.y;
  const int b = bhid >> 4, h = bhid & 15;
  const int t0 = blockIdx.x * 128;

  const short* qb = q + (size_t)bhid * T_DIM * 64;
  const short* kb = k + (size_t)bhid * T_DIM * 64;
  const short* vb = vt + (size_t)bhid * 64 * T_DIM;

  const int lrow8 = lane >> 3;
  const int gph8 = lane & 7;

  // ---- stage Q tile [128][64] ----
#pragma unroll
  for (int jj = 0; jj < 4; ++jj) {
    int j = w * 4 + jj;
    int r = j * 8 + lrow8;
    int gl = (gph8 - (r >> 1)) & 7;
    gl_lds16(qb + (size_t)(t0 + r) * 64 + gl * 8, Qs + j * 512);
  }

  // ---- stage K/V chunks 0,1 into rings 0,1 (wave-private slices) ----
  const int kg = (gph8 - lrow8) & 7;
  const int vd = lane >> 1, vh = lane & 1;
#pragma unroll
  for (int c0 = 0; c0 < 2; ++c0) {
    short* slot = KV + c0 * 8192 + w * 2048;
    const int sg = c0 * 64 + w * 16;
    gl_lds16(kb + (size_t)(sg + lrow8) * 64 + kg * 8, slot);
    gl_lds16(kb + (size_t)(sg + lrow8 + 8) * 64 + kg * 8, slot + 512);
    gl_lds16(vb + (size_t)vd * T_DIM + sg + vh * 8, slot + 1024);
    gl_lds16(vb + (size_t)(vd + 32) * T_DIM + sg + vh * 8, slot + 1536);
  }
  __syncthreads();

  // ---- register-cache Q B-fragments ----
  short8 qa[8][2];
#pragma unroll
  for (int qbk = 0; qbk < 8; ++qbk)
#pragma unroll
    for (int st = 0; st < 2; ++st) {
      int r = qbk * 16 + l15;
      int idx = r * 64 + (((st * 4 + quad) + (r >> 1)) & 7) * 8;
      qa[qbk][st] = *(const short8*)&Qs[idx];
    }

  f32x4 zero = {0.f, 0.f, 0.f, 0.f};
  f32x4 acc[4][8];               // [dblk][qbk] : O^T partial over own s-subset
  float l_part[8];
#pragma unroll
  for (int d = 0; d < 4; ++d)
#pragma unroll
    for (int qb2 = 0; qb2 < 8; ++qb2) acc[d][qb2] = zero;
#pragma unroll
  for (int i = 0; i < 8; ++i) l_part[i] = 0.f;

  for (int c = 0; c < 32; ++c) {
    if (c >= 2) {
      if (c == 31) __builtin_amdgcn_s_waitcnt(0x0F70);   // vmcnt(0)
      else         __builtin_amdgcn_s_waitcnt(0x0F74);   // vmcnt(4)
    }
    const short* slot = KV + (c % 3) * 8192 + w * 2048;

    short8 kf[2];
#pragma unroll
    for (int st = 0; st < 2; ++st)
      kf[st] = *(const short8*)&slot[l15 * 64 + (((st * 4 + quad) + l15) & 7) * 8];
    uint2 vfu[4];
#pragma unroll
    for (int dblk = 0; dblk < 4; ++dblk)
      vfu[dblk] = *(const uint2*)&slot[1024 + (dblk * 16 + l15) * 16 + quad * 4];

    if (c < 30) {
      short* nslot = KV + ((c + 2) % 3) * 8192 + w * 2048;
      const int sg = (c + 2) * 64 + w * 16;
      gl_lds16(kb + (size_t)(sg + lrow8) * 64 + kg * 8, nslot);
      gl_lds16(kb + (size_t)(sg + lrow8 + 8) * 64 + kg * 8, nslot + 512);
      gl_lds16(vb + (size_t)vd * T_DIM + sg + vh * 8, nslot + 1024);
      gl_lds16(vb + (size_t)(vd + 32) * T_DIM + sg + vh * 8, nslot + 1536);
    }

    uint2 pb[8];
#pragma unroll
    for (int qbk = 0; qbk < 8; ++qbk) {
      f32x4 s = zero;
      s = __builtin_amdgcn_mfma_f32_16x16x32_f16(h8(kf[0]), h8(qa[qbk][0]), s, 0, 0, 0);
      s = __builtin_amdgcn_mfma_f32_16x16x32_f16(h8(kf[1]), h8(qa[qbk][1]), s, 0, 0, 0);
      float p0 = __builtin_amdgcn_exp2f(s[0]);
      float p1 = __builtin_amdgcn_exp2f(s[1]);
      float p2 = __builtin_amdgcn_exp2f(s[2]);
      float p3 = __builtin_amdgcn_exp2f(s[3]);
      l_part[qbk] += (p0 + p1) + (p2 + p3);
      pb[qbk].x = pk2(p0, p1);
      pb[qbk].y = pk2(p2, p3);
    }

#pragma unroll
    for (int dblk = 0; dblk < 4; ++dblk) {
      half4 va = __builtin_bit_cast(half4, vfu[dblk]);
#pragma unroll
      for (int qbk = 0; qbk < 8; ++qbk)
        acc[dblk][qbk] = __builtin_amdgcn_mfma_f32_16x16x16f16(
            va, __builtin_bit_cast(half4, pb[qbk]), acc[dblk][qbk], 0, 0, 0);
    }
  }

  // ---- l reduce over quads, publish per-wave ----
#pragma unroll
  for (int qbk = 0; qbk < 8; ++qbk) {
    float l = l_part[qbk];
    l += __shfl_xor(l, 16);
    l += __shfl_xor(l, 32);
    if (quad == 0) l_red[w][qbk * 16 + l15] = l;
  }

  // ---- pairwise O reduce via 64 KB LDS scratch (overlays Qs+KV) ----
  f32x4* Osc = (f32x4*)SMEM;     // 2 regions x 2048 f32x4
  __syncthreads();               // all waves out of the main loop
  if (w & 1) {                   // w1 -> region0, w3 -> region1
    f32x4* dst = Osc + (w >> 1) * 2048;
#pragma unroll
    for (int dblk = 0; dblk < 4; ++dblk)
#pragma unroll
      for (int qbk = 0; qbk < 8; ++qbk)
        dst[(dblk * 8 + qbk) * 64 + lane] = acc[dblk][qbk];
  }
  __syncthreads();
  if (!(w & 1)) {                // w0 += region0, w2 += region1
    f32x4* src = Osc + (w >> 1) * 2048;
#pragma unroll
    for (int dblk = 0; dblk < 4; ++dblk)
#pragma unroll
      for (int qbk = 0; qbk < 8; ++qbk) {
        f32x4 t = src[(dblk * 8 + qbk) * 64 + lane];
        acc[dblk][qbk][0] += t[0]; acc[dblk][qbk][1] += t[1];
        acc[dblk][qbk][2] += t[2]; acc[dblk][qbk][3] += t[3];
      }
  }
  __syncthreads();
  if (w == 2) {
#pragma unroll
    for (int dblk = 0; dblk < 4; ++dblk)
#pragma unroll
      for (int qbk = 0; qbk < 8; ++qbk)
        Osc[(dblk * 8 + qbk) * 64 + lane] = acc[dblk][qbk];
  }
  __syncthreads();
  if (w == 0) {
#pragma unroll
    for (int qbk = 0; qbk < 8; ++qbk) {
      const int qq = qbk * 16 + l15;
      const float lsum = l_red[0][qq] + l_red[1][qq] + l_red[2][qq] + l_red[3][qq];
      const float inv = 1.f / lsum;
      const int t = t0 + qq;
      const size_t mrow = (size_t)(t * 2 + b) * E_DIM;
#pragma unroll
      for (int dblk = 0; dblk < 4; ++dblk) {
        f32x4 t4 = Osc[(dblk * 8 + qbk) * 64 + lane];
        float a0 = acc[dblk][qbk][0] + t4[0];
        float a1 = acc[dblk][qbk][1] + t4[1];
        float a2 = acc[dblk][qbk][2] + t4[2];
        float a3 = acc[dblk][qbk][3] + t4[3];
        uint2 ov;
        ov.x = pk2(a0 * inv, a1 * inv);
        ov.y = pk2(a2 * inv, a3 * inv);
        *(uint2*)&attn[mrow + h * 64 + dblk * 16 + quad * 4] = ov;
      }
    }
  }
}

// ---------------------------------------------------------------------------
extern "C" void kernel_launch(void* const* d_in, const int* in_sizes, int n_in,
                              void* d_out, int out_size, void* d_ws, size_t ws_size,
                              hipStream_t stream)
{
  const float* x  = (const float*)d_in[0];
  const float* wq = (const float*)d_in[1];
  const float* bq = (const float*)d_in[2];
  const float* wk = (const float*)d_in[3];
  const float* bk = (const float*)d_in[4];
  const float* wv = (const float*)d_in[5];
  const float* bv = (const float*)d_in[6];
  const float* wo = (const float*)d_in[7];
  const float* bo = (const float*)d_in[8];
  float* out = (float*)d_out;

  short* ws = (short*)d_ws;
  const size_t M4 = (size_t)M_DIM * E_DIM;   // 4M elems
  const size_t M1 = (size_t)E_DIM * E_DIM;   // 1M elems
  // layout: live-late buffers first, dead-early ones later so fp32 split-K
  // partials can overlay them.
  short* aws  = ws;          // attn out fp16, live until gemm_out
  short* woh  = aws + M4;    // wo fp16, live until gemm_out
  short* xh   = woh + M1;    // dead after gemm_qkv
  short* wqh  = xh + M4;
  short* wkh  = wqh + M1;
  short* wvh  = wkh + M1;
  short* qws  = wvh + M1;    // dead after attn
  short* kws  = qws + M4;
  short* vtws = kws + M4;    // end = 24M shorts = 48 MB
  float* part0 = (float*)xh;           // 16 MB, overlays xh..qws (dead)
  float* part1 = part0 + M4;           // 16 MB, overlays qws..vtws (dead)

  convert_all<<<8192, 256, 0, stream>>>(x, wq, wk, wv, wo, xh, wqh, wkh, wvh, woh);
  gemm_qkv<<<dim3(24, 32), 256, 0, stream>>>(xh, wqh, wkh, wvh, bq, bk, bv,
                                             qws, kws, vtws);
  attn_mfma<<<dim3(16, 32), 256, 0, stream>>>(qws, kws, vtws, aws);
  gemm_out<<<dim3(8, 32, 2), 256, 0, stream>>>(aws, woh, part0, part1);
  add_bias<<<4096, 256, 0, stream>>>(part0, part1, bo, out);
}

// Round 10
// 191.909 us; speedup vs baseline: 2.2930x; 1.0633x over previous
//
#include <hip/hip_runtime.h>
#include <cstddef>
#include <cstdint>

#define T_DIM 2048
#define E_DIM 1024
#define M_DIM 4096   // T*B rows, row index = t*2 + b

typedef __attribute__((ext_vector_type(8))) short short8;      // 8 fp16 bit-patterns
typedef __attribute__((ext_vector_type(8))) _Float16 half8;    // mfma f16 A/B (x32)
typedef __attribute__((ext_vector_type(4))) _Float16 half4;    // mfma f16 A/B (x16)
typedef __attribute__((ext_vector_type(4))) float f32x4;       // mfma C/D

__device__ __forceinline__ short f16_bits(float v) {
  return __builtin_bit_cast(short, (_Float16)v);
}
__device__ __forceinline__ unsigned int pk2(float a, float b) {
  return __builtin_bit_cast(unsigned int, __builtin_amdgcn_cvt_pkrtz(a, b));
}
__device__ __forceinline__ half8 h8(short8 s) { return __builtin_bit_cast(half8, s); }

// async global->LDS, 16B per lane; LDS dest = wave-uniform base + lane*16
__device__ __forceinline__ void gl_lds16(const short* g, const short* l) {
  __builtin_amdgcn_global_load_lds(
      (const __attribute__((address_space(1))) unsigned int*)g,
      (__attribute__((address_space(3))) unsigned int*)l, 16, 0, 0);
}

// ---------------------------------------------------------------------------
// fp32 -> fp16 (RNE). blocks: [0,4096) x ; then 1024 each wq, wk, wv, wo.
// ---------------------------------------------------------------------------
__global__ __launch_bounds__(256) void convert_all(
    const float* __restrict__ x, const float* __restrict__ wq,
    const float* __restrict__ wk, const float* __restrict__ wv,
    const float* __restrict__ wo,
    short* __restrict__ xh, short* __restrict__ wqh, short* __restrict__ wkh,
    short* __restrict__ wvh, short* __restrict__ woh)
{
  const int bid = blockIdx.x;
  const float* in; short* hi; int base;
  if (bid < 4096)      { in = x;  hi = xh;  base = 0;    }
  else if (bid < 5120) { in = wq; hi = wqh; base = 4096; }
  else if (bid < 6144) { in = wk; hi = wkh; base = 5120; }
  else if (bid < 7168) { in = wv; hi = wvh; base = 6144; }
  else                 { in = wo; hi = woh; base = 7168; }
  const int i = (bid - base) * 256 + threadIdx.x;     // float4 index
  float4 v = ((const float4*)in)[i];
  uint2 p;
  p.x = (unsigned short)f16_bits(v.x) | ((unsigned int)(unsigned short)f16_bits(v.y) << 16);
  p.y = (unsigned short)f16_bits(v.z) | ((unsigned int)(unsigned short)f16_bits(v.w) << 16);
  ((uint2*)hi)[i] = p;
}

// ---------------------------------------------------------------------------
// Fused QKV GEMM, fp16, BK=64 (r9, measured-good). C = (A @ W^T + b) * scale.
// ---------------------------------------------------------------------------
__global__ __launch_bounds__(256) void gemm_qkv(
    const short* __restrict__ xh,
    const short* __restrict__ wqh, const short* __restrict__ wkh,
    const short* __restrict__ wvh,
    const float* __restrict__ bq, const float* __restrict__ bk,
    const float* __restrict__ bv,
    short* __restrict__ qo, short* __restrict__ ko, short* __restrict__ vto)
{
  __shared__ __align__(16) short smem[128 * 64 * 2];   // Ah | Wh ; Tb overlays
  short* Ah = smem;
  short* Wh = smem + 8192;
  const int tid = threadIdx.x;
  const int lane = tid & 63;
  const int w = tid >> 6;
  const int quad = lane >> 4;
  const int l15 = lane & 15;
  const int sel = blockIdx.x >> 3;
  const int n0 = (blockIdx.x & 7) * 128;
  const int m0 = blockIdx.y * 128;

  const short* wsel = sel == 0 ? wqh : sel == 1 ? wkh : wvh;
  const float* bias = sel == 0 ? bq : sel == 1 ? bk : bv;
  const float scale = sel == 0 ? 0.125f * 1.44269504088896f : 1.0f;

  const short* gsrc = (w < 2) ? xh : wsel;
  short* lbuf = (w < 2) ? Ah : Wh;
  const int rbase = (w < 2) ? m0 : n0;
  const int lrow8 = lane >> 3;
  const int gph8 = lane & 7;
  const int kg = (gph8 - lrow8) & 7;    // global k-group this lane stages

  f32x4 zero = {0.f, 0.f, 0.f, 0.f};
  f32x4 acc[4][4];
#pragma unroll
  for (int i = 0; i < 4; ++i)
#pragma unroll
    for (int j = 0; j < 4; ++j) acc[i][j] = zero;

  const int wm = w & 1, wn = w >> 1;

  for (int k0 = 0; k0 < E_DIM; k0 += 64) {
    __syncthreads();
#pragma unroll
    for (int jj = 0; jj < 8; ++jj) {
      int j = (w & 1) * 8 + jj;       // 16 staging insts per matrix, 2 waves
      int r = j * 8 + lrow8;          // 0..127
      gl_lds16(gsrc + (size_t)(rbase + r) * E_DIM + k0 + kg * 8, lbuf + j * 512);
    }
    __syncthreads();
#pragma unroll
    for (int ks = 0; ks < 2; ++ks) {
      short8 ahf[4];
#pragma unroll
      for (int i = 0; i < 4; ++i) {
        int r = wm * 64 + i * 16 + l15;
        ahf[i] = *(const short8*)&Ah[r * 64 + ((ks * 4 + quad + r) & 7) * 8];
      }
#pragma unroll
      for (int j = 0; j < 4; ++j) {
        int r = wn * 64 + j * 16 + l15;
        short8 bhf = *(const short8*)&Wh[r * 64 + ((ks * 4 + quad + r) & 7) * 8];
#pragma unroll
        for (int i = 0; i < 4; ++i)
          acc[i][j] = __builtin_amdgcn_mfma_f32_16x16x32_f16(h8(ahf[i]), h8(bhf), acc[i][j], 0, 0, 0);
      }
    }
  }

  if (sel < 2) {
#pragma unroll
    for (int j = 0; j < 4; ++j) {
      const int gc = n0 + wn * 64 + j * 16 + l15;
      const float bb = bias[gc];
      const int h = gc >> 6, d = gc & 63;
      short* dst = sel == 0 ? qo : ko;
#pragma unroll
      for (int i = 0; i < 4; ++i)
#pragma unroll
        for (int reg = 0; reg < 4; ++reg) {
          const int gm = m0 + wm * 64 + i * 16 + quad * 4 + reg;
          const float val = (acc[i][j][reg] + bb) * scale;
          const int t = gm >> 1, b = gm & 1;
          dst[((size_t)(b * 16 + h) * T_DIM + t) * 64 + d] = f16_bits(val);
        }
    }
  } else {
    short* Tb = smem;   // 64 * 128 * 2B = 16KB
    const int by = blockIdx.y;
#pragma unroll
    for (int R = 0; R < 2; ++R) {
      __syncthreads();
      if (wn == R) {
#pragma unroll
        for (int j = 0; j < 4; ++j) {
          const int nl = j * 16 + l15;
          const int gc = n0 + R * 64 + nl;
          const float bb = bias[gc];
#pragma unroll
          for (int i = 0; i < 4; ++i) {
            const int tp = wm * 32 + i * 8 + quad * 2;        // t' base (even)
            unsigned int lo = pk2(acc[i][j][0] + bb, acc[i][j][2] + bb);
            unsigned int hi = pk2(acc[i][j][1] + bb, acc[i][j][3] + bb);
            const int g0 = tp >> 3;
            const int sub = tp & 7;
            *(unsigned int*)&Tb[nl * 128 + ((g0 + nl) & 15) * 8 + sub] = lo;
            *(unsigned int*)&Tb[nl * 128 + ((g0 + 8 + nl) & 15) * 8 + sub] = hi;
          }
        }
      }
      __syncthreads();
#pragma unroll
      for (int ii = 0; ii < 4; ++ii) {
        const int n = w * 16 + ii * 4 + quad;
        const int g = (l15 - n) & 15;
        short8 vvec = *(const short8*)&Tb[n * 128 + l15 * 8];
        const int gc = n0 + R * 64 + n;
        const int h = gc >> 6, d = gc & 63;
        const int b = g >> 3;
        const int t = by * 64 + (g & 7) * 8;
        *(short8*)&vto[((size_t)(b * 16 + h) * 64 + d) * T_DIM + t] = vvec;
      }
    }
  }
}

// ---------------------------------------------------------------------------
// Output projection, fused split-K: 512 threads = 2 groups x 4 waves.
// Group g handles K-half [g*512, g*512+512) with its own 32 KB staging
// region; identical (wm,wn,lane) tiling in both groups. Epilogue: group 1
// publishes acc to the 64 KB LDS scratch, group 0 adds + bias + fp32 store.
// Replaces split-K partials (32 MB wr) + add_bias kernel (48 MB r/w).
// Grid (8,32) = 256 blocks x 512 thr -> 2 blocks/CU (16 waves/CU).
// ---------------------------------------------------------------------------
__global__ __launch_bounds__(512, 4) void gemm_out_fused(
    const short* __restrict__ attn, const short* __restrict__ woh,
    const float* __restrict__ bo, float* __restrict__ out)
{
  __shared__ __align__(16) short smem[32768];   // 64 KB: [g][Ah 16KB | Wh 16KB]
  const int tid = threadIdx.x;
  const int lane = tid & 63;
  const int w = tid >> 6;         // 0..7
  const int g = w >> 2;           // K-half group
  const int wg = w & 3;
  const int quad = lane >> 4;
  const int l15 = lane & 15;
  const int n0 = blockIdx.x * 128;
  const int m0 = blockIdx.y * 128;

  short* Ah = smem + g * 16384;
  short* Wh = Ah + 8192;
  const short* gsrc = (wg < 2) ? attn : woh;
  short* lbuf = (wg < 2) ? Ah : Wh;
  const int rbase = (wg < 2) ? m0 : n0;
  const int lrow8 = lane >> 3;
  const int gph8 = lane & 7;
  const int kg = (gph8 - lrow8) & 7;

  f32x4 zero = {0.f, 0.f, 0.f, 0.f};
  f32x4 acc[4][4];
#pragma unroll
  for (int i = 0; i < 4; ++i)
#pragma unroll
    for (int j = 0; j < 4; ++j) acc[i][j] = zero;

  const int wm = wg & 1, wn = wg >> 1;

  for (int k0 = g * 512; k0 < g * 512 + 512; k0 += 64) {
    __syncthreads();
#pragma unroll
    for (int jj = 0; jj < 8; ++jj) {
      int j = (wg & 1) * 8 + jj;
      int r = j * 8 + lrow8;
      gl_lds16(gsrc + (size_t)(rbase + r) * E_DIM + k0 + kg * 8, lbuf + j * 512);
    }
    __syncthreads();
#pragma unroll
    for (int ks = 0; ks < 2; ++ks) {
      short8 ahf[4];
#pragma unroll
      for (int i = 0; i < 4; ++i) {
        int r = wm * 64 + i * 16 + l15;
        ahf[i] = *(const short8*)&Ah[r * 64 + ((ks * 4 + quad + r) & 7) * 8];
      }
#pragma unroll
      for (int j = 0; j < 4; ++j) {
        int r = wn * 64 + j * 16 + l15;
        short8 bhf = *(const short8*)&Wh[r * 64 + ((ks * 4 + quad + r) & 7) * 8];
#pragma unroll
        for (int i = 0; i < 4; ++i)
          acc[i][j] = __builtin_amdgcn_mfma_f32_16x16x32_f16(h8(ahf[i]), h8(bhf), acc[i][j], 0, 0, 0);
      }
    }
  }

  // ---- cross-group combine via 64 KB LDS scratch ----
  __syncthreads();
  f32x4* Osc = (f32x4*)smem;           // 4096 f32x4
  if (g == 1) {
    f32x4* dst = Osc + wg * 1024;      // 16 KB per wg
#pragma unroll
    for (int i = 0; i < 4; ++i)
#pragma unroll
      for (int j = 0; j < 4; ++j)
        dst[(i * 4 + j) * 64 + lane] = acc[i][j];
  }
  __syncthreads();
  if (g == 0) {
    f32x4* src = Osc + wg * 1024;
#pragma unroll
    for (int j = 0; j < 4; ++j) {
      const int gc = n0 + wn * 64 + j * 16 + l15;
      const float bb = bo[gc];
#pragma unroll
      for (int i = 0; i < 4; ++i) {
        f32x4 t = src[(i * 4 + j) * 64 + lane];
#pragma unroll
        for (int reg = 0; reg < 4; ++reg) {
          const int gm = m0 + wm * 64 + i * 16 + quad * 4 + reg;
          out[(size_t)gm * E_DIM + gc] = acc[i][j][reg] + t[reg] + bb;
        }
      }
    }
  }
}

// ---------------------------------------------------------------------------
// Flash attention v3 (r6/r9 main loop, measured 53 us / WRITE 8 MB).
// Barrier-free main loop, wave-private s-slices, 3-deep ring with ARITHMETIC
// ring indexing (r7/r8: ring_off[] private array -> scratch spill, 218 MB).
// Epilogue: store tail split between w0 (dblk 0,1) and w2 (dblk 2,3) — all
// acc indices compile-time constant.
// ---------------------------------------------------------------------------
__global__ __launch_bounds__(256, 2) void attn_mfma(
    const short* __restrict__ q, const short* __restrict__ k,
    const short* __restrict__ vt, short* __restrict__ attn)
{
  __shared__ __align__(16) short SMEM[32768];   // 64 KB
  __shared__ float l_red[4][128];
  short* Qs = SMEM;            // 16 KB, dead after qa load
  short* KV = SMEM + 8192;     // ring[3] x wave[4] x (K 1024 + V 1024 shorts)

  const int tid = threadIdx.x;
  const int lane = tid & 63;
  const int w = tid >> 6;
  const int quad = lane >> 4;
  const int l15 = lane & 15;
  const int bhid = blockIdx.y;
  const int b = bhid >> 4, h = bhid & 15;
  const int t0 = blockIdx.x * 128;

  const short* qb = q + (size_t)bhid * T_DIM * 64;
  const short* kb = k + (size_t)bhid * T_DIM * 64;
  const short* vb = vt + (size_t)bhid * 64 * T_DIM;

  const int lrow8 = lane >> 3;
  const int gph8 = lane & 7;

  // ---- stage Q tile [128][64] ----
#pragma unroll
  for (int jj = 0; jj < 4; ++jj) {
    int j = w * 4 + jj;
    int r = j * 8 + lrow8;
    int gl = (gph8 - (r >> 1)) & 7;
    gl_lds16(qb + (size_t)(t0 + r) * 64 + gl * 8, Qs + j * 512);
  }

  // ---- stage K/V chunks 0,1 into rings 0,1 (wave-private slices) ----
  const int kg = (gph8 - lrow8) & 7;
  const int vd = lane >> 1, vh = lane & 1;
#pragma unroll
  for (int c0 = 0; c0 < 2; ++c0) {
    short* slot = KV + c0 * 8192 + w * 2048;
    const int sg = c0 * 64 + w * 16;
    gl_lds16(kb + (size_t)(sg + lrow8) * 64 + kg * 8, slot);
    gl_lds16(kb + (size_t)(sg + lrow8 + 8) * 64 + kg * 8, slot + 512);
    gl_lds16(vb + (size_t)vd * T_DIM + sg + vh * 8, slot + 1024);
    gl_lds16(vb + (size_t)(vd + 32) * T_DIM + sg + vh * 8, slot + 1536);
  }
  __syncthreads();

  // ---- register-cache Q B-fragments ----
  short8 qa[8][2];
#pragma unroll
  for (int qbk = 0; qbk < 8; ++qbk)
#pragma unroll
    for (int st = 0; st < 2; ++st) {
      int r = qbk * 16 + l15;
      int idx = r * 64 + (((st * 4 + quad) + (r >> 1)) & 7) * 8;
      qa[qbk][st] = *(const short8*)&Qs[idx];
    }

  f32x4 zero = {0.f, 0.f, 0.f, 0.f};
  f32x4 acc[4][8];               // [dblk][qbk] : O^T partial over own s-subset
  float l_part[8];
#pragma unroll
  for (int d = 0; d < 4; ++d)
#pragma unroll
    for (int qb2 = 0; qb2 < 8; ++qb2) acc[d][qb2] = zero;
#pragma unroll
  for (int i = 0; i < 8; ++i) l_part[i] = 0.f;

  for (int c = 0; c < 32; ++c) {
    if (c >= 2) {
      if (c == 31) __builtin_amdgcn_s_waitcnt(0x0F70);   // vmcnt(0)
      else         __builtin_amdgcn_s_waitcnt(0x0F74);   // vmcnt(4)
    }
    const short* slot = KV + (c % 3) * 8192 + w * 2048;

    short8 kf[2];
#pragma unroll
    for (int st = 0; st < 2; ++st)
      kf[st] = *(const short8*)&slot[l15 * 64 + (((st * 4 + quad) + l15) & 7) * 8];
    uint2 vfu[4];
#pragma unroll
    for (int dblk = 0; dblk < 4; ++dblk)
      vfu[dblk] = *(const uint2*)&slot[1024 + (dblk * 16 + l15) * 16 + quad * 4];

    if (c < 30) {
      short* nslot = KV + ((c + 2) % 3) * 8192 + w * 2048;
      const int sg = (c + 2) * 64 + w * 16;
      gl_lds16(kb + (size_t)(sg + lrow8) * 64 + kg * 8, nslot);
      gl_lds16(kb + (size_t)(sg + lrow8 + 8) * 64 + kg * 8, nslot + 512);
      gl_lds16(vb + (size_t)vd * T_DIM + sg + vh * 8, nslot + 1024);
      gl_lds16(vb + (size_t)(vd + 32) * T_DIM + sg + vh * 8, nslot + 1536);
    }

    uint2 pb[8];
#pragma unroll
    for (int qbk = 0; qbk < 8; ++qbk) {
      f32x4 s = zero;
      s = __builtin_amdgcn_mfma_f32_16x16x32_f16(h8(kf[0]), h8(qa[qbk][0]), s, 0, 0, 0);
      s = __builtin_amdgcn_mfma_f32_16x16x32_f16(h8(kf[1]), h8(qa[qbk][1]), s, 0, 0, 0);
      float p0 = __builtin_amdgcn_exp2f(s[0]);
      float p1 = __builtin_amdgcn_exp2f(s[1]);
      float p2 = __builtin_amdgcn_exp2f(s[2]);
      float p3 = __builtin_amdgcn_exp2f(s[3]);
      l_part[qbk] += (p0 + p1) + (p2 + p3);
      pb[qbk].x = pk2(p0, p1);
      pb[qbk].y = pk2(p2, p3);
    }

#pragma unroll
    for (int dblk = 0; dblk < 4; ++dblk) {
      half4 va = __builtin_bit_cast(half4, vfu[dblk]);
#pragma unroll
      for (int qbk = 0; qbk < 8; ++qbk)
        acc[dblk][qbk] = __builtin_amdgcn_mfma_f32_16x16x16f16(
            va, __builtin_bit_cast(half4, pb[qbk]), acc[dblk][qbk], 0, 0, 0);
    }
  }

  // ---- l reduce over quads, publish per-wave ----
#pragma unroll
  for (int qbk = 0; qbk < 8; ++qbk) {
    float l = l_part[qbk];
    l += __shfl_xor(l, 16);
    l += __shfl_xor(l, 32);
    if (quad == 0) l_red[w][qbk * 16 + l15] = l;
  }

  // ---- pairwise O reduce via 64 KB LDS scratch (overlays Qs+KV) ----
  f32x4* Osc = (f32x4*)SMEM;     // regions of 1024/2048 f32x4
  __syncthreads();               // all waves out of the main loop
  if (w & 1) {                   // w1 -> region0, w3 -> region1
    f32x4* dst = Osc + (w >> 1) * 2048;
#pragma unroll
    for (int dblk = 0; dblk < 4; ++dblk)
#pragma unroll
      for (int qbk = 0; qbk < 8; ++qbk)
        dst[(dblk * 8 + qbk) * 64 + lane] = acc[dblk][qbk];
  }
  __syncthreads();
  if (!(w & 1)) {                // w0 += region0 (all dblk), w2 += region1
    f32x4* src = Osc + (w >> 1) * 2048;
#pragma unroll
    for (int dblk = 0; dblk < 4; ++dblk)
#pragma unroll
      for (int qbk = 0; qbk < 8; ++qbk) {
        f32x4 t = src[(dblk * 8 + qbk) * 64 + lane];
        acc[dblk][qbk][0] += t[0]; acc[dblk][qbk][1] += t[1];
        acc[dblk][qbk][2] += t[2]; acc[dblk][qbk][3] += t[3];
      }
  }
  __syncthreads();
  // swap-publish: w2 gives its dblk 0,1 to w0; w0 gives its dblk 2,3 to w2
  if (w == 2) {
#pragma unroll
    for (int d2 = 0; d2 < 2; ++d2)
#pragma unroll
      for (int qbk = 0; qbk < 8; ++qbk)
        Osc[(d2 * 8 + qbk) * 64 + lane] = acc[d2][qbk];
  }
  if (w == 0) {
#pragma unroll
    for (int d2 = 0; d2 < 2; ++d2)
#pragma unroll
      for (int qbk = 0; qbk < 8; ++qbk)
        Osc[1024 + (d2 * 8 + qbk) * 64 + lane] = acc[2 + d2][qbk];
  }
  __syncthreads();
  if (w == 0) {                  // stores dblk 0,1
#pragma unroll
    for (int qbk = 0; qbk < 8; ++qbk) {
      const int qq = qbk * 16 + l15;
      const float lsum = l_red[0][qq] + l_red[1][qq] + l_red[2][qq] + l_red[3][qq];
      const float inv = 1.f / lsum;
      const int t = t0 + qq;
      const size_t mrow = (size_t)(t * 2 + b) * E_DIM;
#pragma unroll
      for (int d2 = 0; d2 < 2; ++d2) {
        f32x4 t4 = Osc[(d2 * 8 + qbk) * 64 + lane];
        uint2 ov;
        ov.x = pk2((acc[d2][qbk][0] + t4[0]) * inv, (acc[d2][qbk][1] + t4[1]) * inv);
        ov.y = pk2((acc[d2][qbk][2] + t4[2]) * inv, (acc[d2][qbk][3] + t4[3]) * inv);
        *(uint2*)&attn[mrow + h * 64 + d2 * 16 + quad * 4] = ov;
      }
    }
  }
  if (w == 2) {                  // stores dblk 2,3
#pragma unroll
    for (int qbk = 0; qbk < 8; ++qbk) {
      const int qq = qbk * 16 + l15;
      const float lsum = l_red[0][qq] + l_red[1][qq] + l_red[2][qq] + l_red[3][qq];
      const float inv = 1.f / lsum;
      const int t = t0 + qq;
      const size_t mrow = (size_t)(t * 2 + b) * E_DIM;
#pragma unroll
      for (int d2 = 0; d2 < 2; ++d2) {
        f32x4 t4 = Osc[1024 + (d2 * 8 + qbk) * 64 + lane];
        uint2 ov;
        ov.x = pk2((acc[2 + d2][qbk][0] + t4[0]) * inv, (acc[2 + d2][qbk][1] + t4[1]) * inv);
        ov.y = pk2((acc[2 + d2][qbk][2] + t4[2]) * inv, (acc[2 + d2][qbk][3] + t4[3]) * inv);
        *(uint2*)&attn[mrow + h * 64 + (2 + d2) * 16 + quad * 4] = ov;
      }
    }
  }
}

// ---------------------------------------------------------------------------
extern "C" void kernel_launch(void* const* d_in, const int* in_sizes, int n_in,
                              void* d_out, int out_size, void* d_ws, size_t ws_size,
                              hipStream_t stream)
{
  const float* x  = (const float*)d_in[0];
  const float* wq = (const float*)d_in[1];
  const float* bq = (const float*)d_in[2];
  const float* wk = (const float*)d_in[3];
  const float* bk = (const float*)d_in[4];
  const float* wv = (const float*)d_in[5];
  const float* bv = (const float*)d_in[6];
  const float* wo = (const float*)d_in[7];
  const float* bo = (const float*)d_in[8];
  float* out = (float*)d_out;

  short* ws = (short*)d_ws;
  const size_t M4 = (size_t)M_DIM * E_DIM;   // 4M elems
  const size_t M1 = (size_t)E_DIM * E_DIM;   // 1M elems
  short* aws  = ws;          // attn out fp16, live until gemm_out
  short* woh  = aws + M4;    // wo fp16, live until gemm_out
  short* xh   = woh + M1;
  short* wqh  = xh + M4;
  short* wkh  = wqh + M1;
  short* wvh  = wkh + M1;
  short* qws  = wvh + M1;
  short* kws  = qws + M4;
  short* vtws = kws + M4;    // end = 24M shorts = 48 MB

  convert_all<<<8192, 256, 0, stream>>>(x, wq, wk, wv, wo, xh, wqh, wkh, wvh, woh);
  gemm_qkv<<<dim3(24, 32), 256, 0, stream>>>(xh, wqh, wkh, wvh, bq, bk, bv,
                                             qws, kws, vtws);
  attn_mfma<<<dim3(16, 32), 256, 0, stream>>>(qws, kws, vtws, aws);
  gemm_out_fused<<<dim3(8, 32), 512, 0, stream>>>(aws, woh, bo, out);
}